// Round 11
// baseline (273.523 us; speedup 1.0000x reference)
//
#include <hip/hip_runtime.h>
#include <hip/hip_bf16.h>

typedef __attribute__((ext_vector_type(8))) __bf16 bf16x8;
typedef __attribute__((ext_vector_type(4))) float  f32x4;

#define SDIM 49
#define NDIM 1024
#define CDIM 384
#define KDIM 384            // GEMM contraction dims (x-part only)
#define DMC  64
#define NSTEP 6             // KDIM / 64
#define SCALE (1.0f/(SDIM*NDIM))
#define SLOT 65536          // A(keys) 32KB + B(q) 32KB per K-step slot; 2 slots = 128KB

__device__ __forceinline__ void gload16(const void* g, void* l) {
    __builtin_amdgcn_global_load_lds((const __attribute__((address_space(1))) void*)g,
                                     (__attribute__((address_space(3))) void*)l, 16, 0, 0);
}

// ---------------------------------------------------------------------------
// pack + passthrough copy; x-part (384) -> dst rows of 384; mc -> mcm[1024][128].
// ---------------------------------------------------------------------------
__global__ __launch_bounds__(512) void pack_copy_kernel(
    const float* __restrict__ xloc, const float* __restrict__ mv,
    const float* __restrict__ cv,   __hip_bfloat16* __restrict__ dst,
    __hip_bfloat16* __restrict__ mcm, float* __restrict__ cpy)
{
    const int j = blockIdx.x;
    const int d = threadIdx.x;
    if (d < CDIM) {
        float vals[SDIM];
        const float* p = xloc + ((size_t)j * CDIM + d) * SDIM;
        #pragma unroll
        for (int s = 0; s < SDIM; ++s) vals[s] = p[s];
        float* dcp = cpy + ((size_t)j * CDIM + d) * SDIM;
        #pragma unroll
        for (int s = 0; s < SDIM; ++s) dcp[s] = vals[s];
        #pragma unroll
        for (int s = 0; s < SDIM; ++s)
            dst[((size_t)s * NDIM + j) * KDIM + d] = __float2bfloat16(vals[s]);
    } else {
        const float v = (d < CDIM + DMC) ? mv[j * DMC + (d - CDIM)]
                                         : cv[j * DMC + (d - CDIM - DMC)];
        mcm[j * 128 + (d - CDIM)] = __float2bfloat16(v);
    }
}

// f [N,512] -> Fm [N,384] bf16 + fmc [N,128] bf16
__global__ void fpack_kernel(const float* __restrict__ f,
                             __hip_bfloat16* __restrict__ Fm,
                             __hip_bfloat16* __restrict__ fmc, int n)
{
    int i = blockIdx.x * blockDim.x + threadIdx.x;
    if (i >= n) return;
    const int r = i >> 9, d = i & 511;
    const __hip_bfloat16 v = __float2bfloat16(f[i]);
    if (d < CDIM) Fm[r * CDIM + d] = v;
    else          fmc[r * 128 + (d - CDIM)] = v;
}

// ---------------------------------------------------------------------------
// M precompute: M[0][q][key] = fmc[q]·mcp[key], M[1][q][key] = mct[q]·mcp[key]
// (K=128).  Same fragment maps as loss kernel (A=keys, B=queries,
// mfma_f32_16x16x32_bf16; C/D col=lane&15, row=(lane>>4)*4+reg).
// grid 64 blocks (qt=bid>>3, kt=bid&7) of 256 (4 waves = 2 wk x 2 wq).
// ---------------------------------------------------------------------------
__global__ __launch_bounds__(256) void mker_kernel(
    const __hip_bfloat16* __restrict__ fmc, const __hip_bfloat16* __restrict__ mct,
    const __hip_bfloat16* __restrict__ mcp, float* __restrict__ M)
{
    const int bid = blockIdx.x;
    const int qt = bid >> 3, kt = bid & 7;
    const int tid = threadIdx.x, lane = tid & 63, wv = tid >> 6;
    const int l15 = lane & 15, l4 = lane >> 4;
    const int wk = wv >> 1, wq = wv & 1;

    const char* Ab = (const char*)mcp;   // [1024][128] bf16 -> 256 B rows
    const char* B1 = (const char*)fmc;
    const char* B2 = (const char*)mct;

    f32x4 acc1[4][4], acc2[4][4];
    #pragma unroll
    for (int a = 0; a < 4; ++a)
        #pragma unroll
        for (int b = 0; b < 4; ++b) { acc1[a][b] = f32x4{}; acc2[a][b] = f32x4{}; }

    #pragma unroll
    for (int kc = 0; kc < 4; ++kc) {
        const int kco = kc * 64 + l4 * 16;
        bf16x8 af[4], b1f[4], b2f[4];
        #pragma unroll
        for (int a = 0; a < 4; ++a) {
            const int j = kt * 128 + wk * 64 + a * 16 + l15;
            af[a] = *(const bf16x8*)(Ab + j * 256 + kco);
        }
        #pragma unroll
        for (int b = 0; b < 4; ++b) {
            const int i = qt * 128 + wq * 64 + b * 16 + l15;
            b1f[b] = *(const bf16x8*)(B1 + i * 256 + kco);
            b2f[b] = *(const bf16x8*)(B2 + i * 256 + kco);
        }
        #pragma unroll
        for (int a = 0; a < 4; ++a)
            #pragma unroll
            for (int b = 0; b < 4; ++b) {
                acc1[a][b] = __builtin_amdgcn_mfma_f32_16x16x32_bf16(af[a], b1f[b], acc1[a][b], 0, 0, 0);
                acc2[a][b] = __builtin_amdgcn_mfma_f32_16x16x32_bf16(af[a], b2f[b], acc2[a][b], 0, 0, 0);
            }
    }
    #pragma unroll
    for (int a = 0; a < 4; ++a)
        #pragma unroll
        for (int b = 0; b < 4; ++b) {
            const size_t q   = qt * 128 + wq * 64 + b * 16 + l15;
            const size_t key = kt * 128 + wk * 64 + a * 16 + l4 * 4;
            *(f32x4*)(M + (q << 10) + key) = acc1[a][b];
            *(f32x4*)(M + (1u << 20) + (q << 10) + key) = acc2[a][b];
        }
}

// ---------------------------------------------------------------------------
// PERSISTENT fused GEMM + partial-LSE (R10 minimal-sync schedule), K=384,
// acc initialized from the s-invariant mc-product M (f32 [2][1024][1024]).
// grid = 256 blocks of 512 (8 waves = 2 wk x 4 wq); block (xcd=bid&7, jj)
// owns tiles g = 196*xcd + jj + 32k.  Tile g: s=g>>5, kb=(g>>3)&3, qb=g&7.
// Tile: 256 keys x 256 q, BK=64 (6 K-steps); wave tile 128 keys x 64 q.
// LDS slot: A rows [256][128B] @0, B rows [256][128B] @32K; content[row][col]
// = G[row][kstep*128 + (col ^ ((row&7)<<4))]; linear LDS dest + pre-swizzled
// global source (0 bank conflicts, validated R4-R10).  Row stride now 768 B.
// ---------------------------------------------------------------------------
__global__ __launch_bounds__(512, 2) void loss_kernel(
    const __hip_bfloat16* __restrict__ Fm,   // [N,384]
    const __hip_bfloat16* __restrict__ Km,   // [S,N,384] keys
    const __hip_bfloat16* __restrict__ Qm,   // [S,N,384] queries (pred2 x-part)
    const float* __restrict__ M,             // [2][1024][1024] (q, key)
    float2* __restrict__ part,               // [S*2048][8]
    float* __restrict__ out)
{
    extern __shared__ __attribute__((aligned(16))) char sm[];   // 2*SLOT

    const int bid = blockIdx.x;
    const int xcd = bid & 7;
    const int jj  = bid >> 3;
    const int g0  = 196 * xcd;
    const int gend = g0 + 196;

    const int tid  = threadIdx.x;
    const int lane = tid & 63;
    const int w    = tid >> 6;
    const int l15  = lane & 15;
    const int l4   = lane >> 4;   // 0..3
    const int wk   = w >> 2;      // 0..1 key half
    const int wq   = w & 3;       // 0..3 q quarter

    const int trow = tid >> 3;
    const int scol = (((tid & 7) ^ ((tid >> 3) & 7)) << 4);

    const unsigned xo   = (unsigned)((l15 & 7) << 4);
    const unsigned arow = (unsigned)((wk * 128 + l15) * 128);
    const unsigned brow = 32768u + (unsigned)((wq * 64 + l15) * 128);

    auto APtr = [&](int g) -> const char* {
        const int s = g >> 5, kb = (g >> 3) & 3;
        return (const char*)Km + ((size_t)s * NDIM + (size_t)kb * 256) * (KDIM * 2);
    };
    auto BPtr = [&](int g) -> const char* {
        const int s = g >> 5, qb = g & 7;
        return (qb < 4)
            ? ((const char*)Fm + (size_t)qb * 256 * (KDIM * 2))
            : ((const char*)Qm + ((size_t)s * NDIM + (size_t)(qb - 4) * 256) * (KDIM * 2));
    };
    auto stage8 = [&](const char* A, const char* B, int ko, char* slot) {
        #pragma unroll
        for (int c = 0; c < 4; ++c) {
            gload16(A + (size_t)(c * 64 + trow) * (KDIM * 2) + ko + scol,
                    slot + c * 8192 + tid * 16);
            gload16(B + (size_t)(c * 64 + trow) * (KDIM * 2) + ko + scol,
                    slot + 32768 + c * 8192 + tid * 16);
        }
    };

    f32x4 acc[8][4];
    bf16x8 afr[8], bfr[4];

    #define READ12(KC) do {                                                   \
        const unsigned co = ((unsigned)((KC) * 64 + l4 * 16)) ^ xo;           \
        _Pragma("unroll")                                                     \
        for (int a = 0; a < 8; ++a)                                           \
            afr[a] = *(const bf16x8*)(sb_ + arow + a * 2048u + co);           \
        _Pragma("unroll")                                                     \
        for (int b = 0; b < 4; ++b)                                           \
            bfr[b] = *(const bf16x8*)(sb_ + brow + b * 2048u + co);           \
    } while (0)

    #define MFMA32() do {                                                     \
        _Pragma("unroll")                                                     \
        for (int a = 0; a < 8; ++a)                                           \
            _Pragma("unroll")                                                 \
            for (int b = 0; b < 4; ++b)                                       \
                acc[a][b] = __builtin_amdgcn_mfma_f32_16x16x32_bf16(          \
                    afr[a], bfr[b], acc[a][b], 0, 0, 0);                      \
    } while (0)

    // prologue: first tile's step 0 into slot 0
    stage8(APtr(g0 + jj), BPtr(g0 + jj), 0, sm);

    for (int g = g0 + jj; g < gend; g += 32) {
        const char* Ag = APtr(g);
        const char* Bg = BPtr(g);
        const bool hasNext = (g + 32) < gend;
        const char* An = hasNext ? APtr(g + 32) : Ag;
        const char* Bn = hasNext ? BPtr(g + 32) : Bg;

        const int s  = g >> 5;
        const int kb = (g >> 3) & 3;
        const int qb = g & 7;

        // ---- acc init = s-invariant mc-product (loads overlap step-0 wait)
        {
            const float* Mp = M + ((size_t)(qb >= 4) << 20);
            const int qloc   = (qb & 3) * 256 + wq * 64 + l15;
            const int keyloc = kb * 256 + wk * 128 + l4 * 4;
            #pragma unroll
            for (int a = 0; a < 8; ++a)
                #pragma unroll
                for (int b = 0; b < 4; ++b)
                    acc[a][b] = *(const f32x4*)(Mp + ((size_t)(qloc + b * 16) << 10)
                                                + keyloc + a * 16);
        }

        #pragma unroll
        for (int t = 0; t < NSTEP; ++t) {
            const char* sb_ = sm + (size_t)(t & 1) * SLOT;
            char* ns_ = sm + (size_t)((t + 1) & 1) * SLOT;

            __syncthreads();   // vmcnt0+lgkm0 drain = slot handoff (R10)

            if ((t < NSTEP - 1) || hasNext) {
                const char* sA = (t < NSTEP - 1) ? Ag : An;
                const char* sB = (t < NSTEP - 1) ? Bg : Bn;
                stage8(sA, sB, (t < NSTEP - 1) ? (t + 1) * 128 : 0, ns_);
            }
            __builtin_amdgcn_sched_barrier(0);   // pin stage-issue first

            READ12(0);
            __builtin_amdgcn_s_setprio(1); MFMA32(); __builtin_amdgcn_s_setprio(0);
            READ12(1);
            __builtin_amdgcn_s_setprio(1); MFMA32(); __builtin_amdgcn_s_setprio(0);
        }

        // ---- epilogue (overlaps next tile's in-flight step-0 loads)
        float q_m[4], q_s[4];
        #pragma unroll
        for (int b = 0; b < 4; ++b) {
            float m = -3.0e38f;
            #pragma unroll
            for (int a = 0; a < 8; ++a)
                #pragma unroll
                for (int r = 0; r < 4; ++r) m = fmaxf(m, acc[a][b][r]);
            float ss = 0.0f;
            #pragma unroll
            for (int a = 0; a < 8; ++a)
                #pragma unroll
                for (int r = 0; r < 4; ++r) ss += __expf(acc[a][b][r] - m);
            #pragma unroll
            for (int off = 16; off <= 32; off <<= 1) {
                float mo = __shfl_xor(m, off, 64);
                float so = __shfl_xor(ss, off, 64);
                float nm = fmaxf(m, mo);
                ss = ss * __expf(m - nm) + so * __expf(mo - nm);
                m = nm;
            }
            q_m[b] = m; q_s[b] = ss;
        }
        if (lane < 16) {
            const size_t rowb = (size_t)s * 2048 + (size_t)qb * 256 + wq * 64 + lane;
            #pragma unroll
            for (int b = 0; b < 4; ++b)
                part[(rowb + b * 16) * 8 + kb * 2 + wk] = make_float2(q_m[b], q_s[b]);
        }

        if (kb == (qb & 3) && (wq >> 1) == wk) {
            float d = 0.0f;
            const bool lok = (((lane >> 2) & 3) == l4);
            if (wq & 1) {
                #pragma unroll
                for (int b = 0; b < 4; ++b)
                    #pragma unroll
                    for (int r = 0; r < 4; ++r)
                        if (lok && r == (lane & 3)) d += acc[4 + b][b][r];
            } else {
                #pragma unroll
                for (int b = 0; b < 4; ++b)
                    #pragma unroll
                    for (int r = 0; r < 4; ++r)
                        if (lok && r == (lane & 3)) d += acc[b][b][r];
            }
            #pragma unroll
            for (int off = 1; off < 64; off <<= 1) d += __shfl_xor(d, off, 64);
            if (lane == 0) atomicAdd(out, -d * SCALE);
        }
    }
    #undef READ12
    #undef MFMA32
}

// merge the 8 per-(kb,wk) partials of each row -> lse, accumulate loss
__global__ __launch_bounds__(256) void reduce_kernel(
    const float2* __restrict__ part, float* __restrict__ out)
{
    const int row = blockIdx.x * 256 + threadIdx.x;   // 392*256 = 100352 rows
    const float2* p = part + (size_t)row * 8;
    float m = -3.0e38f;
    float2 q[8];
    #pragma unroll
    for (int i = 0; i < 8; ++i) { q[i] = p[i]; m = fmaxf(m, q[i].x); }
    float ssum = 0.0f;
    #pragma unroll
    for (int i = 0; i < 8; ++i) ssum += q[i].y * __expf(q[i].x - m);
    float v = m + __logf(ssum);
    #pragma unroll
    for (int off = 1; off < 64; off <<= 1) v += __shfl_xor(v, off, 64);
    __shared__ float red[4];
    const int lane = threadIdx.x & 63, w = threadIdx.x >> 6;
    if (lane == 0) red[w] = v;
    __syncthreads();
    if (threadIdx.x == 0)
        atomicAdd(out, (red[0] + red[1] + red[2] + red[3]) * SCALE);
}

extern "C" void kernel_launch(void* const* d_in, const int* in_sizes, int n_in,
                              void* d_out, int out_size, void* d_ws, size_t ws_size,
                              hipStream_t stream)
{
    (void)in_sizes; (void)n_in; (void)out_size; (void)ws_size;
    const float* f  = (const float*)d_in[0];
    const float* x  = (const float*)d_in[1];
    const float* xp = (const float*)d_in[2];
    const float* mt = (const float*)d_in[3];
    const float* mp = (const float*)d_in[4];
    const float* ct = (const float*)d_in[5];
    const float* cp = (const float*)d_in[6];
    float* out = (float*)d_out;

    char* ws = (char*)d_ws;
    const size_t packBytes = (size_t)SDIM * NDIM * KDIM * 2;   // 38.5 MB
    __hip_bfloat16* Km  = (__hip_bfloat16*)ws;
    __hip_bfloat16* Qm  = (__hip_bfloat16*)(ws + packBytes);
    char* p2 = ws + 2 * packBytes;
    __hip_bfloat16* Fm  = (__hip_bfloat16*)p2;                 p2 += (size_t)NDIM * KDIM * 2;
    __hip_bfloat16* fmc = (__hip_bfloat16*)p2;                 p2 += (size_t)NDIM * 128 * 2;
    __hip_bfloat16* mcp = (__hip_bfloat16*)p2;                 p2 += (size_t)NDIM * 128 * 2;
    __hip_bfloat16* mct = (__hip_bfloat16*)p2;                 p2 += (size_t)NDIM * 128 * 2;
    float* M            = (float*)p2;                          p2 += (size_t)2 * NDIM * NDIM * 4;
    float2* part        = (float2*)p2;

    hipMemsetAsync(out, 0, sizeof(float), stream);

    const int sz = NDIM * CDIM * SDIM;
    pack_copy_kernel<<<NDIM, 512, 0, stream>>>(xp, mp, cp, Km, mcp, out + 1);
    pack_copy_kernel<<<NDIM, 512, 0, stream>>>(x,  mt, ct, Qm, mct, out + 1 + sz);
    fpack_kernel<<<(NDIM * 512 + 255) / 256, 256, 0, stream>>>(f, Fm, fmc, NDIM * 512);
    mker_kernel<<<64, 256, 0, stream>>>(fmc, mct, mcp, M);

    loss_kernel<<<256, 512, 2 * SLOT, stream>>>(Fm, Km, Qm, M, part, out);
    reduce_kernel<<<392, 256, 0, stream>>>(part, out);
}